// Round 1
// baseline (51931.781 us; speedup 1.0000x reference)
//
#include <hip/hip_runtime.h>
#include <hip/hip_bf16.h>
#include <cstddef>

// GRU (Keras reset_after=True):
//   rg = h @ w_rec + b_rec ; z = sig(xz+rz); r = sig(xr+rr)
//   hh = tanh(xh + r*rh)   ; h' = z*h + (1-z)*hh
// xg[b,t,:] == M[ids[b,t],:] where M = emb @ w_in + b_in  (VOCAB=128 -> 1.5MB table)

#define VOCABN 128
#define EMBEDN 256
#define HIDN   1024
#define BN     64
#define TN     1024
#define C3N    3072

// ---------------- M table: M[v][c] = sum_e emb[v][e] * w_in[e][c] + b_in[c] ----
__global__ __launch_bounds__(256, 1) void emb_gemm(
    const float* __restrict__ emb, const float* __restrict__ w_in,
    const float* __restrict__ b_in, float* __restrict__ Mtab)
{
    __shared__ float se[16][256];
    const int tid = threadIdx.x;
    const int c   = blockIdx.x * 256 + tid;   // 12 blocks in x
    const int v0  = blockIdx.y * 16;          // 8 blocks in y
#pragma unroll
    for (int i = 0; i < 16; ++i) {
        int flat = i * 256 + tid;             // 4096 elements
        int r = flat >> 8, e = flat & 255;
        se[r][e] = emb[(v0 + r) * 256 + e];
    }
    __syncthreads();
    float acc[16];
#pragma unroll
    for (int r = 0; r < 16; ++r) acc[r] = 0.f;
    for (int e = 0; e < 256; ++e) {
        float w = w_in[(size_t)e * C3N + c];
#pragma unroll
        for (int r = 0; r < 16; ++r) acc[r] = fmaf(se[r][e], w, acc[r]);
    }
    float bc = b_in[c];
#pragma unroll
    for (int r = 0; r < 16; ++r)
        Mtab[(size_t)(v0 + r) * C3N + c] = acc[r] + bc;
}

// ---------------- one GRU timestep ------------------------------------------
// grid 256 blocks x 512 threads. Block bid owns j = bid*4 .. bid*4+3.
// thread: b = tid&63, jj = (tid>>6)&3, kh = tid>>8 (k parity split).
__global__ __launch_bounds__(512, 1) void gru_step(
    const int* __restrict__ ids, const float* __restrict__ Mtab,
    const float* __restrict__ w_rec, const float* __restrict__ b_rec,
    const float* __restrict__ h_prev, float* __restrict__ h_next,
    __hip_bfloat16* __restrict__ hs_t, int t)
{
    __shared__ float sh[64][129];     // h chunk, padded: bank = (b + k) % 32
    __shared__ float sred[256][3];
    const int tid = threadIdx.x;
    const int b   = tid & 63;
    const int jj  = (tid >> 6) & 3;
    const int kh  = tid >> 8;                       // 0 or 1
    const int j   = blockIdx.x * 4 + jj;
    const int ju  = __builtin_amdgcn_readfirstlane(j);  // wave-uniform -> s_load

    float az = 0.f, ar = 0.f, ah = 0.f;
    for (int cch = 0; cch < 8; ++cch) {
        const int kc = cch * 128;
#pragma unroll
        for (int i = 0; i < 16; ++i) {
            int flat = i * 512 + tid;               // 8192 elements
            int bb = flat >> 7, kk = flat & 127;
            sh[bb][kk] = h_prev[bb * HIDN + kc + kk];
        }
        __syncthreads();
#pragma unroll 8
        for (int i = 0; i < 64; ++i) {
            int kk = 2 * i + kh;
            float hv = sh[b][kk];
            size_t base = (size_t)(kc + kk) * C3N;
            az = fmaf(hv, w_rec[base + ju], az);
            ar = fmaf(hv, w_rec[base + HIDN + ju], ar);
            ah = fmaf(hv, w_rec[base + 2 * HIDN + ju], ah);
        }
        __syncthreads();
    }
    if (kh == 1) {
        sred[tid - 256][0] = az;
        sred[tid - 256][1] = ar;
        sred[tid - 256][2] = ah;
    }
    __syncthreads();
    if (kh == 0) {
        az += sred[tid][0]; ar += sred[tid][1]; ah += sred[tid][2];
        float rz = az + b_rec[ju];
        float rr = ar + b_rec[HIDN + ju];
        float rh = ah + b_rec[2 * HIDN + ju];
        const int id = ids[b * TN + t];
        const float* Mr = Mtab + (size_t)id * C3N;
        float xz = Mr[j], xr = Mr[HIDN + j], xh = Mr[2 * HIDN + j];
        float z  = 1.f / (1.f + expf(-(xz + rz)));
        float r  = 1.f / (1.f + expf(-(xr + rr)));
        float hh = tanhf(xh + r * rh);
        float hp = h_prev[b * HIDN + j];
        float hn = z * hp + (1.f - z) * hh;
        h_next[b * HIDN + j] = hn;
        if (hs_t) hs_t[b * HIDN + j] = __float2bfloat16(hn);
    }
}

// ---------------- final logits GEMM from stored hs (bf16) -------------------
// hs layout [t][b][j]; row m = t*64 + b. out[b][t][v].
__global__ __launch_bounds__(256, 1) void out_gemm(
    const __hip_bfloat16* __restrict__ hs, const float* __restrict__ w_out,
    const float* __restrict__ b_out, float* __restrict__ out)
{
    __shared__ float sa[8][1024];
    const int tid = threadIdx.x;
    const int m0  = blockIdx.x * 8;
#pragma unroll
    for (int i = 0; i < 32; ++i) {
        int flat = i * 256 + tid;                    // 8192
        int r = flat >> 10, k = flat & 1023;
        sa[r][k] = __bfloat162float(hs[(size_t)(m0 + r) * HIDN + k]);
    }
    __syncthreads();
    const int v = tid & 127;
    const int half = tid >> 7;
    float a0 = 0.f, a1 = 0.f, a2 = 0.f, a3 = 0.f;
    for (int k = 0; k < 1024; ++k) {
        float w = w_out[k * VOCABN + v];
        a0 = fmaf(sa[half * 4 + 0][k], w, a0);
        a1 = fmaf(sa[half * 4 + 1][k], w, a1);
        a2 = fmaf(sa[half * 4 + 2][k], w, a2);
        a3 = fmaf(sa[half * 4 + 3][k], w, a3);
    }
    float bo = b_out[v];
    float accs[4] = {a0, a1, a2, a3};
#pragma unroll
    for (int q = 0; q < 4; ++q) {
        int m = m0 + half * 4 + q;
        out[((size_t)(m & 63) * TN + (m >> 6)) * VOCABN + v] = accs[q] + bo;
    }
}

// ---------------- fallback: per-step logits from f32 h (small ws) -----------
__global__ __launch_bounds__(256, 1) void logits_step(
    const float* __restrict__ h, const float* __restrict__ w_out,
    const float* __restrict__ b_out, float* __restrict__ out, int t)
{
    __shared__ float sa[8][1024];
    const int tid = threadIdx.x;
    const int b0  = blockIdx.x * 8;                 // grid 8
#pragma unroll
    for (int i = 0; i < 32; ++i) {
        int flat = i * 256 + tid;
        int r = flat >> 10, k = flat & 1023;
        sa[r][k] = h[(size_t)(b0 + r) * HIDN + k];
    }
    __syncthreads();
    const int v = tid & 127;
    const int half = tid >> 7;
    float a0 = 0.f, a1 = 0.f, a2 = 0.f, a3 = 0.f;
    for (int k = 0; k < 1024; ++k) {
        float w = w_out[k * VOCABN + v];
        a0 = fmaf(sa[half * 4 + 0][k], w, a0);
        a1 = fmaf(sa[half * 4 + 1][k], w, a1);
        a2 = fmaf(sa[half * 4 + 2][k], w, a2);
        a3 = fmaf(sa[half * 4 + 3][k], w, a3);
    }
    float bo = b_out[v];
    float accs[4] = {a0, a1, a2, a3};
#pragma unroll
    for (int q = 0; q < 4; ++q) {
        int bb = b0 + half * 4 + q;
        out[((size_t)bb * TN + t) * VOCABN + v] = accs[q] + bo;
    }
}

extern "C" void kernel_launch(void* const* d_in, const int* in_sizes, int n_in,
                              void* d_out, int out_size, void* d_ws, size_t ws_size,
                              hipStream_t stream) {
    const int*   ids   = (const int*)d_in[0];
    const float* emb   = (const float*)d_in[1];
    const float* w_in  = (const float*)d_in[2];
    const float* b_in  = (const float*)d_in[3];
    const float* w_rec = (const float*)d_in[4];
    const float* b_rec = (const float*)d_in[5];
    const float* w_out = (const float*)d_in[6];
    const float* b_out = (const float*)d_in[7];
    float* out = (float*)d_out;

    char* ws = (char*)d_ws;
    float* Mtab = (float*)ws;
    size_t off = (size_t)VOCABN * C3N * 4;          // 1.5 MB
    float* h0 = (float*)(ws + off); off += (size_t)BN * HIDN * 4;
    float* h1 = (float*)(ws + off); off += (size_t)BN * HIDN * 4;
    __hip_bfloat16* hs = (__hip_bfloat16*)(ws + off);
    const size_t need_hs = (size_t)TN * BN * HIDN * 2;   // 128 MB
    const bool pathA = (ws_size >= off + need_hs);

    emb_gemm<<<dim3(12, 8), 256, 0, stream>>>(emb, w_in, b_in, Mtab);
    hipMemsetAsync(h0, 0, (size_t)BN * HIDN * 4, stream);

    for (int t = 0; t < TN; ++t) {
        float* hp = (t & 1) ? h1 : h0;
        float* hn = (t & 1) ? h0 : h1;
        gru_step<<<256, 512, 0, stream>>>(
            ids, Mtab, w_rec, b_rec, hp, hn,
            pathA ? (hs + (size_t)t * BN * HIDN) : (__hip_bfloat16*)nullptr, t);
        if (!pathA)
            logits_step<<<8, 256, 0, stream>>>(hn, w_out, b_out, out, t);
    }
    if (pathA)
        out_gemm<<<(BN * TN) / 8, 256, 0, stream>>>(hs, w_out, b_out, out);
}

// Round 2
// 6934.885 us; speedup vs baseline: 7.4885x; 7.4885x over previous
//
#include <hip/hip_runtime.h>
#include <hip/hip_bf16.h>
#include <hip/hip_fp16.h>
#include <cstddef>

// GRU (Keras reset_after=True), persistent-kernel design:
//   64 WGs (1/CU), WG w owns hidden units [16w,16w+16) -> 48 gate cols.
//   W_rec slice fp16 in LDS, pre-arranged in MFMA B-fragment order.
//   h_t broadcast via LLC (sc0 sc1 bypass L2), comm layout == MFMA A-fragment
//   order, per-WG step flags (no barrier), double-buffered by step parity.
//   xg[b,t,:] == Mtab[ids[b,t],:],  Mtab = emb @ w_in + b_in (128x3072 fp32).

#define VOCABN 128
#define EMBEDN 256
#define HIDN   1024
#define BN     64
#define TN     1024
#define C3N    3072
#define NWG    64

typedef _Float16 half8 __attribute__((ext_vector_type(8)));
typedef float    f32x4 __attribute__((ext_vector_type(4)));
typedef unsigned int u32x4 __attribute__((ext_vector_type(4)));

// dynamic LDS layout (bytes)
#define LDS_W     0         // 3*32*64*8 halves = 98304 B  (B-frags: [nt][kt][lane][8])
#define LDS_MTAB  98304     // 128*48 halves    = 12288 B
#define LDS_OWN   110592    // 64*16 halves     =  2048 B
#define LDS_BYTES 112640

// ---------------- Mtab: M[v][c] = sum_e emb[v][e]*w_in[e][c] + b_in[c] ------
__global__ __launch_bounds__(256, 1) void emb_gemm(
    const float* __restrict__ emb, const float* __restrict__ w_in,
    const float* __restrict__ b_in, float* __restrict__ Mtab)
{
    __shared__ float se[16][256];
    const int tid = threadIdx.x;
    const int c   = blockIdx.x * 256 + tid;   // 12 x
    const int v0  = blockIdx.y * 16;          // 8 y
#pragma unroll
    for (int i = 0; i < 16; ++i) {
        int flat = i * 256 + tid;
        int r = flat >> 8, e = flat & 255;
        se[r][e] = emb[(v0 + r) * 256 + e];
    }
    __syncthreads();
    float acc[16];
#pragma unroll
    for (int r = 0; r < 16; ++r) acc[r] = 0.f;
    for (int e = 0; e < 256; ++e) {
        float w = w_in[(size_t)e * C3N + c];
#pragma unroll
        for (int r = 0; r < 16; ++r) acc[r] = fmaf(se[r][e], w, acc[r]);
    }
    float bc = b_in[c];
#pragma unroll
    for (int r = 0; r < 16; ++r)
        Mtab[(size_t)(v0 + r) * C3N + c] = acc[r] + bc;
}

// ---------------- persistent GRU over all T ---------------------------------
__global__ __launch_bounds__(256, 1) void gru_persist(
    const int* __restrict__ ids, const float* __restrict__ Mtab_g,
    const float* __restrict__ w_rec, const float* __restrict__ b_rec,
    _Float16* __restrict__ comm,        // 2 * 65536 halves (256 KB)
    unsigned int* __restrict__ flags,   // 64 u32
    _Float16* __restrict__ hs)          // [T][B][H] fp16
{
    extern __shared__ char smem[];
    _Float16* wlds  = (_Float16*)(smem + LDS_W);
    _Float16* mtab  = (_Float16*)(smem + LDS_MTAB);
    _Float16* own16 = (_Float16*)(smem + LDS_OWN);
    const half8* wp = (const half8*)wlds;

    const int tid = threadIdx.x;
    const int w   = blockIdx.x;           // 0..63, owns hidden [16w,16w+16)
    const int mt  = tid >> 6;             // wave id = M-tile (batch group of 16)
    const int l   = tid & 63;             // lane
    const int jj  = l & 15;
    const int lh  = l >> 4;

    // ---- startup: W_rec slice -> LDS in B-frag order --------------------
    for (int i = 0; i < 192; ++i) {
        int flat = i * 256 + tid;                       // 49152 = 3*32*64*8
        int e  = flat & 7;
        int ll = (flat >> 3) & 63;
        int kt = (flat >> 9) & 31;
        int nt = flat >> 14;                            // 0..2
        int k   = kt * 32 + (ll >> 4) * 8 + e;
        int col = nt * 1024 + w * 16 + (ll & 15);
        wlds[((nt * 32 + kt) * 64 + ll) * 8 + e] = (_Float16)w_rec[(size_t)k * C3N + col];
    }
    // ---- Mtab slice -> LDS fp16 -----------------------------------------
    for (int i = 0; i < 24; ++i) {
        int flat = i * 256 + tid;                       // 6144 = 128*48
        int v = flat / 48, c = flat % 48;
        int col = (c >> 4) * 1024 + w * 16 + (c & 15);
        mtab[v * 48 + c] = (_Float16)Mtab_g[(size_t)v * C3N + col];
    }
    const float bz = b_rec[w * 16 + jj];
    const float br = b_rec[1024 + w * 16 + jj];
    const float bh = b_rec[2048 + w * 16 + jj];
    __syncthreads();

    float hprev[4] = {0.f, 0.f, 0.f, 0.f};
    const int bbase = mt * 16 + lh * 4;

    for (int t = 0; t < TN; ++t) {
        // ---- poll: all producers published h_t (flag >= t) --------------
        {
            const unsigned int tv = (unsigned int)t;
            while (true) {
                unsigned int f;
                asm volatile("global_load_dword %0, %1, off sc0 sc1\n\t"
                             "s_waitcnt vmcnt(0)"
                             : "=v"(f) : "v"(flags + l) : "memory");
                if (__all(f >= tv)) break;
                __builtin_amdgcn_s_sleep(1);
            }
        }
        __builtin_amdgcn_sched_barrier(0);

        // ---- load phase: 4 ids (cached) + 32 h A-frags (LLC bypass) -----
        unsigned int idsv[4];
#pragma unroll
        for (int q = 0; q < 4; ++q) {
            const int* ip = ids + (size_t)(bbase + q) * TN + t;
            asm volatile("global_load_dword %0, %1, off"
                         : "=v"(idsv[q]) : "v"(ip) : "memory");
        }
        u32x4 hf[32];
        const _Float16* cbase = comm + (size_t)(t & 1) * 65536 + mt * 16384 + l * 8;
#pragma unroll
        for (int kt = 0; kt < 32; ++kt) {
            const _Float16* p = cbase + kt * 512;
            asm volatile("global_load_dwordx4 %0, %1, off sc0 sc1"
                         : "=v"(hf[kt]) : "v"(p) : "memory");
        }

        f32x4 acc0 = {0.f, 0.f, 0.f, 0.f};
        f32x4 acc1 = {0.f, 0.f, 0.f, 0.f};
        f32x4 acc2 = {0.f, 0.f, 0.f, 0.f};

        asm volatile("s_waitcnt vmcnt(20)" ::: "memory");   // ids + hf[0..11]
        __builtin_amdgcn_sched_barrier(0);
#pragma unroll
        for (int kt = 0; kt < 12; ++kt) {
            half8 a = __builtin_bit_cast(half8, hf[kt]);
            acc0 = __builtin_amdgcn_mfma_f32_16x16x32_f16(a, wp[(0 * 32 + kt) * 64 + l], acc0, 0, 0, 0);
            acc1 = __builtin_amdgcn_mfma_f32_16x16x32_f16(a, wp[(1 * 32 + kt) * 64 + l], acc1, 0, 0, 0);
            acc2 = __builtin_amdgcn_mfma_f32_16x16x32_f16(a, wp[(2 * 32 + kt) * 64 + l], acc2, 0, 0, 0);
        }
        asm volatile("s_waitcnt vmcnt(8)" ::: "memory");    // + hf[12..23]
        __builtin_amdgcn_sched_barrier(0);
#pragma unroll
        for (int kt = 12; kt < 24; ++kt) {
            half8 a = __builtin_bit_cast(half8, hf[kt]);
            acc0 = __builtin_amdgcn_mfma_f32_16x16x32_f16(a, wp[(0 * 32 + kt) * 64 + l], acc0, 0, 0, 0);
            acc1 = __builtin_amdgcn_mfma_f32_16x16x32_f16(a, wp[(1 * 32 + kt) * 64 + l], acc1, 0, 0, 0);
            acc2 = __builtin_amdgcn_mfma_f32_16x16x32_f16(a, wp[(2 * 32 + kt) * 64 + l], acc2, 0, 0, 0);
        }
        asm volatile("s_waitcnt vmcnt(0)" ::: "memory");    // rest + ids done
        __builtin_amdgcn_sched_barrier(0);
#pragma unroll
        for (int kt = 24; kt < 32; ++kt) {
            half8 a = __builtin_bit_cast(half8, hf[kt]);
            acc0 = __builtin_amdgcn_mfma_f32_16x16x32_f16(a, wp[(0 * 32 + kt) * 64 + l], acc0, 0, 0, 0);
            acc1 = __builtin_amdgcn_mfma_f32_16x16x32_f16(a, wp[(1 * 32 + kt) * 64 + l], acc1, 0, 0, 0);
            acc2 = __builtin_amdgcn_mfma_f32_16x16x32_f16(a, wp[(2 * 32 + kt) * 64 + l], acc2, 0, 0, 0);
        }

        // ---- gates (C layout: col=lane&15, row=(lane>>4)*4+q, m89) ------
#pragma unroll
        for (int q = 0; q < 4; ++q) {
            float az = acc0[q], ar = acc1[q], ah = acc2[q];
            int id = (int)idsv[q];
            float xz = (float)mtab[id * 48 + jj];
            float xr = (float)mtab[id * 48 + 16 + jj];
            float xh = (float)mtab[id * 48 + 32 + jj];
            float z  = 1.f / (1.f + __expf(-(xz + az + bz)));
            float r  = 1.f / (1.f + __expf(-(xr + ar + br)));
            float hh = tanhf(xh + r * (ah + bh));
            float hn = z * hprev[q] + (1.f - z) * hh;
            hprev[q] = hn;
            own16[(bbase + q) * 16 + jj] = (_Float16)hn;
        }
        __syncthreads();

        // ---- pack + publish h_{t+1} slice + hs ---------------------------
        if (tid < 128) {
            int b = tid >> 1, hf2 = tid & 1;
            u32x4 val = *(const u32x4*)&own16[b * 16 + hf2 * 8];
            _Float16* cp = comm + (size_t)((t + 1) & 1) * 65536
                         + (size_t)(((b >> 4) * 32 + (w >> 1)) * 64
                                    + ((b & 15) + 16 * (2 * (w & 1) + hf2))) * 8;
            asm volatile("global_store_dwordx4 %0, %1, off sc0 sc1"
                         :: "v"(cp), "v"(val) : "memory");
            _Float16* hp2 = hs + ((size_t)t * 64 + b) * 1024 + w * 16 + hf2 * 8;
            *(u32x4*)hp2 = val;
        }
        asm volatile("s_waitcnt vmcnt(0)" ::: "memory");
        __syncthreads();
        if (tid == 0) {
            unsigned int fv = (unsigned int)(t + 1);
            asm volatile("global_store_dword %0, %1, off sc0 sc1"
                         :: "v"(flags + w), "v"(fv) : "memory");
        }
    }
}

// ---------------- logits: hs[T*B,H] fp16 @ w_out + b_out --------------------
__global__ __launch_bounds__(256, 2) void out_gemm(
    const _Float16* __restrict__ hs, const float* __restrict__ w_out,
    const float* __restrict__ b_out, float* __restrict__ out)
{
    __shared__ float sa[16][1024];
    const int tid = threadIdx.x;
    const int m0  = blockIdx.x * 16;
#pragma unroll
    for (int i = 0; i < 8; ++i) {
        int flat = i * 256 + tid;                 // 2048 chunks of 8 halves
        int r = flat >> 7, kc = flat & 127;
        half8 hv = *(const half8*)(hs + (size_t)(m0 + r) * 1024 + kc * 8);
#pragma unroll
        for (int e = 0; e < 8; ++e) sa[r][kc * 8 + e] = (float)hv[e];
    }
    __syncthreads();
    const int v = tid & 127, g = tid >> 7;
    float acc[8];
#pragma unroll
    for (int r = 0; r < 8; ++r) acc[r] = 0.f;
    for (int k = 0; k < 1024; ++k) {
        float wv = w_out[(size_t)k * VOCABN + v];
#pragma unroll
        for (int r = 0; r < 8; ++r) acc[r] = fmaf(sa[g * 8 + r][k], wv, acc[r]);
    }
    float bo = b_out[v];
#pragma unroll
    for (int r = 0; r < 8; ++r) {
        int m = m0 + g * 8 + r;
        out[((size_t)(m & 63) * TN + (m >> 6)) * VOCABN + v] = acc[r] + bo;
    }
}

extern "C" void kernel_launch(void* const* d_in, const int* in_sizes, int n_in,
                              void* d_out, int out_size, void* d_ws, size_t ws_size,
                              hipStream_t stream) {
    const int*   ids   = (const int*)d_in[0];
    const float* emb   = (const float*)d_in[1];
    const float* w_in  = (const float*)d_in[2];
    const float* b_in  = (const float*)d_in[3];
    const float* w_rec = (const float*)d_in[4];
    const float* b_rec = (const float*)d_in[5];
    const float* w_out = (const float*)d_in[6];
    const float* b_out = (const float*)d_in[7];
    float* out = (float*)d_out;

    char* ws = (char*)d_ws;
    float* Mtab = (float*)ws;                              // 1.5 MB
    size_t off = (size_t)VOCABN * C3N * 4;
    _Float16* comm = (_Float16*)(ws + off); off += (size_t)2 * 65536 * 2;  // 256 KB
    unsigned int* flags = (unsigned int*)(ws + off); off += 4096;
    _Float16* hs = (_Float16*)(ws + off);                  // 128 MB

    hipFuncSetAttribute(reinterpret_cast<const void*>(gru_persist),
                        hipFuncAttributeMaxDynamicSharedMemorySize, LDS_BYTES);

    emb_gemm<<<dim3(12, 8), 256, 0, stream>>>(emb, w_in, b_in, Mtab);
    hipMemsetAsync(comm, 0, (size_t)2 * 65536 * 2, stream);
    hipMemsetAsync(flags, 0, NWG * 4, stream);

    gru_persist<<<NWG, 256, LDS_BYTES, stream>>>(ids, Mtab, w_rec, b_rec,
                                                 comm, flags, hs);
    out_gemm<<<(BN * TN) / 16, 256, 0, stream>>>(hs, w_out, b_out, out);
}

// Round 4
// 5551.078 us; speedup vs baseline: 9.3553x; 1.2493x over previous
//
#include <hip/hip_runtime.h>
#include <hip/hip_bf16.h>
#include <hip/hip_fp16.h>
#include <cstddef>

// GRU (Keras reset_after=True), persistent kernel, per-wave sync planes.
//   64 WGs (1/CU), WG w owns hidden units [16w,16w+16) -> 48 gate cols.
//   Wave mt of WG w handles batches [16mt,16mt+16): consumes ONLY producer
//   waves mt of all WGs -> 4 independent 64-wave sync groups, no barriers.
//   W_z,W_r fp16 in REGISTERS (B-frag order), W_h fp16 in LDS.
//   h broadcast via LLC (sc0 sc1), comm layout == MFMA A-frag order.
//   xg[b,t,:] == Mtab[ids[b,t],:],  Mtab = emb @ w_in + b_in.

#define VOCABN 128
#define HIDN   1024
#define BN     64
#define TN     1024
#define C3N    3072
#define NWG    64

typedef _Float16 half8 __attribute__((ext_vector_type(8)));
typedef float    f32x4 __attribute__((ext_vector_type(4)));
typedef unsigned int u32x4 __attribute__((ext_vector_type(4)));

// ---------------- Mtab: M[v][c] = sum_e emb[v][e]*w_in[e][c] + b_in[c] ------
__global__ __launch_bounds__(256, 1) void emb_gemm(
    const float* __restrict__ emb, const float* __restrict__ w_in,
    const float* __restrict__ b_in, float* __restrict__ Mtab)
{
    __shared__ float se[16][256];
    const int tid = threadIdx.x;
    const int c   = blockIdx.x * 256 + tid;   // 12 x
    const int v0  = blockIdx.y * 16;          // 8 y
#pragma unroll
    for (int i = 0; i < 16; ++i) {
        int flat = i * 256 + tid;
        int r = flat >> 8, e = flat & 255;
        se[r][e] = emb[(v0 + r) * 256 + e];
    }
    __syncthreads();
    float acc[16];
#pragma unroll
    for (int r = 0; r < 16; ++r) acc[r] = 0.f;
    for (int e = 0; e < 256; ++e) {
        float w = w_in[(size_t)e * C3N + c];
#pragma unroll
        for (int r = 0; r < 16; ++r) acc[r] = fmaf(se[r][e], w, acc[r]);
    }
    float bc = b_in[c];
#pragma unroll
    for (int r = 0; r < 16; ++r)
        Mtab[(size_t)(v0 + r) * C3N + c] = acc[r] + bc;
}

// ---------------- persistent GRU over all T ---------------------------------
__global__ __launch_bounds__(256, 1) void gru_persist(
    const int* __restrict__ ids, const float* __restrict__ Mtab_g,
    const float* __restrict__ w_rec, const float* __restrict__ b_rec,
    _Float16* __restrict__ comm,        // 2 * 65536 halves (256 KB)
    unsigned int* __restrict__ flags,   // 256 flags * 16 u32 stride (16 KB)
    _Float16* __restrict__ hs)          // [T][B][H] fp16
{
    __shared__ _Float16 wh[32 * 64 * 8];      // 32 KB, B-frags [kt][lane][8]
    __shared__ _Float16 mtab[VOCABN * 48];    // 12 KB
    const half8* whp = (const half8*)wh;

    const int tid = threadIdx.x;
    const int w   = blockIdx.x;           // 0..63, owns hidden [16w,16w+16)
    const int mt  = tid >> 6;             // wave id = batch group of 16
    const int l   = tid & 63;
    const int jj  = l & 15;
    const int lh  = l >> 4;

    // ---- LDS init: W_h (candidate gate) in B-frag order ------------------
    // 16384 halves = 64 iterations x 256 threads  (R3 bug: was 128 -> OOB)
    for (int i = 0; i < 64; ++i) {
        int flat = i * 256 + tid;                       // < 16384 = 32*64*8
        int e  = flat & 7;
        int ll = (flat >> 3) & 63;
        int kt = flat >> 9;                             // 0..31
        int k   = kt * 32 + (ll >> 4) * 8 + e;          // 0..1023
        int col = 2048 + w * 16 + (ll & 15);
        wh[(kt * 64 + ll) * 8 + e] = (_Float16)w_rec[(size_t)k * C3N + col];
    }
    for (int i = 0; i < 24; ++i) {
        int flat = i * 256 + tid;                       // 6144 = 128*48
        int v = flat / 48, c = flat % 48;
        int col = (c >> 4) * 1024 + w * 16 + (c & 15);
        mtab[v * 48 + c] = (_Float16)Mtab_g[(size_t)v * C3N + col];
    }
    // ---- register weights: z and r gates, B-frag order -------------------
    half8 wz[32], wr[32];
#pragma unroll
    for (int kt = 0; kt < 32; ++kt) {
#pragma unroll
        for (int e = 0; e < 8; ++e) {
            int k = kt * 32 + lh * 8 + e;
            wz[kt][e] = (_Float16)w_rec[(size_t)k * C3N + w * 16 + jj];
            wr[kt][e] = (_Float16)w_rec[(size_t)k * C3N + 1024 + w * 16 + jj];
        }
    }
    const float bz = b_rec[w * 16 + jj];
    const float br = b_rec[1024 + w * 16 + jj];
    const float bh = b_rec[2048 + w * 16 + jj];
    __syncthreads();                                    // LDS ready; last barrier

    const int bbase = mt * 16 + lh * 4;
    float hprev[4] = {0.f, 0.f, 0.f, 0.f};

    // producer store base: element h[b][j], j=w*16+jj -> frag coords
    const int ktp = w >> 1;
    const int lp  = 16 * ((w & 1) * 2 + (jj >> 3));
    _Float16* cw_base = comm + (size_t)mt * 16384 + ktp * 512 + lp * 8 + (jj & 7);
    const _Float16* cr_base = comm + (size_t)mt * 16384 + (size_t)l * 8;
    unsigned int* myflag = flags + (w * 4 + mt) * 16;
    const unsigned int* pollp = flags + (l * 4 + mt) * 16;

    int idsv[4];
#pragma unroll
    for (int q = 0; q < 4; ++q) idsv[q] = ids[(size_t)(bbase + q) * TN];

    for (int t = 0; t < TN; ++t) {
        // ---- poll: 64 producer-waves of my plane published h_t -----------
        {
            const unsigned int tv = (unsigned int)t;
            while (true) {
                unsigned int f;
                asm volatile("global_load_dword %0, %1, off sc0 sc1\n\t"
                             "s_waitcnt vmcnt(0)"
                             : "=v"(f) : "v"(pollp) : "memory");
                if (__all(f >= tv)) break;
                __builtin_amdgcn_s_sleep(1);
            }
        }
        __builtin_amdgcn_sched_barrier(0);

        const _Float16* cr = cr_base + (size_t)(t & 1) * 65536;
        u32x4 hfA[8], hfB[8];
#pragma unroll
        for (int i = 0; i < 8; ++i)
            asm volatile("global_load_dwordx4 %0, %1, off sc0 sc1"
                         : "=v"(hfA[i]) : "v"(cr + i * 512) : "memory");
#pragma unroll
        for (int i = 0; i < 8; ++i)
            asm volatile("global_load_dwordx4 %0, %1, off sc0 sc1"
                         : "=v"(hfB[i]) : "v"(cr + (8 + i) * 512) : "memory");

        f32x4 acc0 = {0.f, 0.f, 0.f, 0.f};
        f32x4 acc1 = {0.f, 0.f, 0.f, 0.f};
        f32x4 acc2 = {0.f, 0.f, 0.f, 0.f};

        asm volatile("s_waitcnt vmcnt(8)" ::: "memory");        // blk0 ready
        __builtin_amdgcn_sched_barrier(0);
#pragma unroll
        for (int i = 0; i < 8; ++i) {
            half8 a = __builtin_bit_cast(half8, hfA[i]);
            acc0 = __builtin_amdgcn_mfma_f32_16x16x32_f16(a, wz[i], acc0, 0, 0, 0);
            acc1 = __builtin_amdgcn_mfma_f32_16x16x32_f16(a, wr[i], acc1, 0, 0, 0);
            acc2 = __builtin_amdgcn_mfma_f32_16x16x32_f16(a, whp[i * 64 + l], acc2, 0, 0, 0);
        }
#pragma unroll
        for (int i = 0; i < 8; ++i)                              // blk2 -> A
            asm volatile("global_load_dwordx4 %0, %1, off sc0 sc1"
                         : "=v"(hfA[i]) : "v"(cr + (16 + i) * 512) : "memory");
        asm volatile("s_waitcnt vmcnt(8)" ::: "memory");        // blk1 ready
        __builtin_amdgcn_sched_barrier(0);
#pragma unroll
        for (int i = 0; i < 8; ++i) {
            half8 a = __builtin_bit_cast(half8, hfB[i]);
            acc0 = __builtin_amdgcn_mfma_f32_16x16x32_f16(a, wz[8 + i], acc0, 0, 0, 0);
            acc1 = __builtin_amdgcn_mfma_f32_16x16x32_f16(a, wr[8 + i], acc1, 0, 0, 0);
            acc2 = __builtin_amdgcn_mfma_f32_16x16x32_f16(a, whp[(8 + i) * 64 + l], acc2, 0, 0, 0);
        }
#pragma unroll
        for (int i = 0; i < 8; ++i)                              // blk3 -> B
            asm volatile("global_load_dwordx4 %0, %1, off sc0 sc1"
                         : "=v"(hfB[i]) : "v"(cr + (24 + i) * 512) : "memory");
        asm volatile("s_waitcnt vmcnt(8)" ::: "memory");        // blk2 ready
        __builtin_amdgcn_sched_barrier(0);
#pragma unroll
        for (int i = 0; i < 8; ++i) {
            half8 a = __builtin_bit_cast(half8, hfA[i]);
            acc0 = __builtin_amdgcn_mfma_f32_16x16x32_f16(a, wz[16 + i], acc0, 0, 0, 0);
            acc1 = __builtin_amdgcn_mfma_f32_16x16x32_f16(a, wr[16 + i], acc1, 0, 0, 0);
            acc2 = __builtin_amdgcn_mfma_f32_16x16x32_f16(a, whp[(16 + i) * 64 + l], acc2, 0, 0, 0);
        }
        asm volatile("s_waitcnt vmcnt(0)" ::: "memory");        // blk3 ready
        __builtin_amdgcn_sched_barrier(0);
#pragma unroll
        for (int i = 0; i < 8; ++i) {
            half8 a = __builtin_bit_cast(half8, hfB[i]);
            acc0 = __builtin_amdgcn_mfma_f32_16x16x32_f16(a, wz[24 + i], acc0, 0, 0, 0);
            acc1 = __builtin_amdgcn_mfma_f32_16x16x32_f16(a, wr[24 + i], acc1, 0, 0, 0);
            acc2 = __builtin_amdgcn_mfma_f32_16x16x32_f16(a, whp[(24 + i) * 64 + l], acc2, 0, 0, 0);
        }

        // ---- gates (C layout: col=lane&15, row=(lane>>4)*4+q) ------------
        float hnv[4];
#pragma unroll
        for (int q = 0; q < 4; ++q) {
            float az = acc0[q], ar = acc1[q], ah = acc2[q];
            int id = idsv[q];
            float xz = (float)mtab[id * 48 + jj];
            float xr = (float)mtab[id * 48 + 16 + jj];
            float xh = (float)mtab[id * 48 + 32 + jj];
            float z  = 1.f / (1.f + __expf(-(xz + az + bz)));
            float r  = 1.f / (1.f + __expf(-(xr + ar + br)));
            float hh = tanhf(xh + r * (ah + bh));
            float hn = z * hprev[q] + (1.f - z) * hh;
            hprev[q] = hn;
            hnv[q] = hn;
        }
        // ---- publish h_{t+1}: 4 x 2B direct stores in A-frag layout ------
        _Float16* cwp = cw_base + (size_t)((t + 1) & 1) * 65536;
#pragma unroll
        for (int q = 0; q < 4; ++q) {
            unsigned int hv = (unsigned int)__builtin_bit_cast(
                unsigned short, (_Float16)hnv[q]);
            asm volatile("global_store_short %0, %1, off sc0 sc1"
                         :: "v"(cwp + (lh * 4 + q) * 8), "v"(hv) : "memory");
        }
        // hs stores (plain cached, off the flag critical path)
#pragma unroll
        for (int q = 0; q < 4; ++q)
            hs[((size_t)t * BN + (bbase + q)) * HIDN + w * 16 + jj] = (_Float16)hnv[q];
        asm volatile("s_waitcnt vmcnt(4)" ::: "memory");        // comm stores done
        // prefetch next-step ids (independent of flags)
        if (t + 1 < TN) {
#pragma unroll
            for (int q = 0; q < 4; ++q)
                idsv[q] = ids[(size_t)(bbase + q) * TN + t + 1];
        }
        if (l == 0) {
            unsigned int fv = (unsigned int)(t + 1);
            asm volatile("global_store_dword %0, %1, off sc0 sc1"
                         :: "v"(myflag), "v"(fv) : "memory");
        }
    }
}

// ---------------- logits: hs[T*B,H] fp16 @ w_out + b_out --------------------
__global__ __launch_bounds__(256, 2) void out_gemm(
    const _Float16* __restrict__ hs, const float* __restrict__ w_out,
    const float* __restrict__ b_out, float* __restrict__ out)
{
    __shared__ float sa[16][1024];
    const int tid = threadIdx.x;
    const int m0  = blockIdx.x * 16;
#pragma unroll
    for (int i = 0; i < 8; ++i) {
        int flat = i * 256 + tid;
        int r = flat >> 7, kc = flat & 127;
        half8 hv = *(const half8*)(hs + (size_t)(m0 + r) * 1024 + kc * 8);
#pragma unroll
        for (int e = 0; e < 8; ++e) sa[r][kc * 8 + e] = (float)hv[e];
    }
    __syncthreads();
    const int v = tid & 127, g = tid >> 7;
    float acc[8];
#pragma unroll
    for (int r = 0; r < 8; ++r) acc[r] = 0.f;
    for (int k = 0; k < 1024; ++k) {
        float wv = w_out[(size_t)k * VOCABN + v];
#pragma unroll
        for (int r = 0; r < 8; ++r) acc[r] = fmaf(sa[g * 8 + r][k], wv, acc[r]);
    }
    float bo = b_out[v];
#pragma unroll
    for (int r = 0; r < 8; ++r) {
        int m = m0 + g * 8 + r;
        out[((size_t)(m & 63) * TN + (m >> 6)) * VOCABN + v] = acc[r] + bo;
    }
}

extern "C" void kernel_launch(void* const* d_in, const int* in_sizes, int n_in,
                              void* d_out, int out_size, void* d_ws, size_t ws_size,
                              hipStream_t stream) {
    const int*   ids   = (const int*)d_in[0];
    const float* emb   = (const float*)d_in[1];
    const float* w_in  = (const float*)d_in[2];
    const float* b_in  = (const float*)d_in[3];
    const float* w_rec = (const float*)d_in[4];
    const float* b_rec = (const float*)d_in[5];
    const float* w_out = (const float*)d_in[6];
    const float* b_out = (const float*)d_in[7];
    float* out = (float*)d_out;

    char* ws = (char*)d_ws;
    float* Mtab = (float*)ws;                              // 1.5 MB
    size_t off = (size_t)VOCABN * C3N * 4;
    _Float16* comm = (_Float16*)(ws + off); off += (size_t)2 * 65536 * 2;  // 256 KB
    unsigned int* flags = (unsigned int*)(ws + off); off += 256 * 16 * 4;  // 16 KB
    _Float16* hs = (_Float16*)(ws + off);                  // 128 MB

    emb_gemm<<<dim3(12, 8), 256, 0, stream>>>(emb, w_in, b_in, Mtab);
    hipMemsetAsync(comm, 0, (size_t)2 * 65536 * 2, stream);
    hipMemsetAsync(flags, 0, 256 * 16 * 4, stream);

    gru_persist<<<NWG, 256, 0, stream>>>(ids, Mtab, w_rec, b_rec,
                                         comm, flags, hs);
    out_gemm<<<(BN * TN) / 16, 256, 0, stream>>>(hs, w_out, b_out, out);
}